// Round 3
// baseline (230.822 us; speedup 1.0000x reference)
//
#include <hip/hip_runtime.h>
#include <hip/hip_bf16.h>

// Problem constants
#define NH    12      // heads
#define HD    64      // head dim
#define NT    576     // tokens (queries)
#define CC    768     // channels
#define M_TOT 13914   // total KV tokens per head (90 special + 72*192 cache)
#define MP    13952   // M padded to multiple of 64
#define NTIL  218     // MP / 64
#define NEW0  13338   // where the 576 new k/v tokens land in Kf/Vt

typedef short bf16x8 __attribute__((ext_vector_type(8)));
typedef float f32x4 __attribute__((ext_vector_type(4)));

// ---------------------------------------------------------------------------
// f32 -> bf16 bulk convert (8 elems/thread)
// ---------------------------------------------------------------------------
__global__ __launch_bounds__(256) void cvt_bf16(
    const float* __restrict__ src, __hip_bfloat16* __restrict__ dst, int n8) {
  const int i = blockIdx.x * 256 + threadIdx.x;
  if (i >= n8) return;
  const float4 a = ((const float4*)src)[2 * i];
  const float4 b = ((const float4*)src)[2 * i + 1];
  __hip_bfloat16 t[8];
  t[0] = __float2bfloat16(a.x); t[1] = __float2bfloat16(a.y);
  t[2] = __float2bfloat16(a.z); t[3] = __float2bfloat16(a.w);
  t[4] = __float2bfloat16(b.x); t[5] = __float2bfloat16(b.y);
  t[6] = __float2bfloat16(b.z); t[7] = __float2bfloat16(b.w);
  ((uint4*)dst)[i] = *(const uint4*)t;
}

// ---------------------------------------------------------------------------
// QKV projection via MFMA, no LDS (x and W are L2-resident bf16).
// C[m][c] = xb[m,:] . wb[c,:] + bias[c];  m<576, c<2304, K=768.
// Block: 4 waves; wave w does rows m0+16w..+15, cols n0..n0+63.
// Scatter: q -> Qb (x0.125), k -> Kf[NEW0+m], v -> Vt[d][NEW0+m].
// ---------------------------------------------------------------------------
__global__ __launch_bounds__(256) void gemm_qkv_mfma(
    const __hip_bfloat16* __restrict__ xb, const __hip_bfloat16* __restrict__ wb,
    const float* __restrict__ bias, __hip_bfloat16* __restrict__ Qb,
    __hip_bfloat16* __restrict__ Kf, __hip_bfloat16* __restrict__ Vt) {
  const int tid = threadIdx.x;
  const int w = tid >> 6, l = tid & 63, l15 = l & 15, lg = l >> 4;
  const int n0 = blockIdx.x * 64;
  const int mw = blockIdx.y * 64 + w * 16;

  f32x4 acc[4];
#pragma unroll
  for (int nt = 0; nt < 4; ++nt) acc[nt] = (f32x4){0.f, 0.f, 0.f, 0.f};

  const __hip_bfloat16* arow = xb + (size_t)(mw + l15) * CC + 8 * lg;
#pragma unroll 4
  for (int k0 = 0; k0 < CC; k0 += 32) {
    const bf16x8 a = *(const bf16x8*)(arow + k0);
#pragma unroll
    for (int nt = 0; nt < 4; ++nt) {
      const bf16x8 b =
          *(const bf16x8*)(wb + (size_t)(n0 + nt * 16 + l15) * CC + k0 + 8 * lg);
      acc[nt] = __builtin_amdgcn_mfma_f32_16x16x32_bf16(a, b, acc[nt], 0, 0, 0);
    }
  }

#pragma unroll
  for (int nt = 0; nt < 4; ++nt) {
    const int c = n0 + nt * 16 + l15;
    const int which = c / CC;  // 0=q 1=k 2=v
    const int rem = c - which * CC;
    const int hh = rem >> 6;
    const int dd = rem & 63;
    const float bc = bias[c];
#pragma unroll
    for (int r = 0; r < 4; ++r) {
      const int m = mw + 4 * lg + r;
      const float v = acc[nt][r] + bc;
      if (which == 0) {
        Qb[((size_t)hh * NT + m) * HD + dd] = __float2bfloat16(v * 0.125f);
      } else if (which == 1) {
        Kf[((size_t)hh * MP + NEW0 + m) * HD + dd] = __float2bfloat16(v);
      } else {
        Vt[((size_t)hh * HD + dd) * MP + NEW0 + m] = __float2bfloat16(v);
      }
    }
  }
}

// ---------------------------------------------------------------------------
// Token map per head (verified):
//   [0,72) special | [72,90) frames 8..10 tok 0..5 | [90,1626) frames 0..7
//   [1626,13338) frames 11..71 | [13338,13914) new (from qkv gemm)
// ---------------------------------------------------------------------------
__device__ __forceinline__ const float* kv_src_row(
    const float* __restrict__ cache, const float* __restrict__ special,
    int h, int m) {
  if (m < 72) return special + ((size_t)h * 72 + m) * HD;
  if (m < 90) {
    const int j = m - 72;
    return cache + (((size_t)h * 72 + 8 + j / 6) * 192 + (j % 6)) * HD;
  }
  if (m < 1626) return cache + ((size_t)h * 13824 + (m - 90)) * HD;
  return cache + ((size_t)h * 13824 + 2112 + (m - 1626)) * HD;
}

__global__ __launch_bounds__(256) void gather_k(
    const float* __restrict__ kc, const float* __restrict__ ksp,
    __hip_bfloat16* __restrict__ Kf) {
  const int idx = blockIdx.x * 256 + threadIdx.x;
  const int per_h = NEW0 * 16;
  if (idx >= NH * per_h) return;
  const int h = idx / per_h;
  const int r = idx - h * per_h;
  const int m = r >> 4;
  const int dq = (r & 15) << 2;
  const float4 v = *(const float4*)(kv_src_row(kc, ksp, h, m) + dq);
  __hip_bfloat162* dst = (__hip_bfloat162*)(Kf + ((size_t)h * MP + m) * HD + dq);
  __hip_bfloat162 a, b;
  a.x = __float2bfloat16(v.x); a.y = __float2bfloat16(v.y);
  b.x = __float2bfloat16(v.z); b.y = __float2bfloat16(v.w);
  dst[0] = a; dst[1] = b;
}

// V transpose gather via LDS: coalesced reads AND writes.
// Grid (MP/64, NH): tile of 64 tokens; m >= NEW0 written as zeros
// (gemm_qkv_mfma later fills [NEW0,M_TOT); tail stays zero = pad).
__global__ __launch_bounds__(256) void gather_vt(
    const float* __restrict__ vc, const float* __restrict__ vsp,
    __hip_bfloat16* __restrict__ Vt) {
  __shared__ float vsf[64][68];
  const int h = blockIdx.y;
  const int m0 = blockIdx.x * 64;
  const int tid = threadIdx.x;
#pragma unroll
  for (int p = 0; p < 4; ++p) {
    const int mr = m0 + p * 16 + (tid >> 4);
    const int c4 = (tid & 15) * 4;
    float4 v = make_float4(0.f, 0.f, 0.f, 0.f);
    if (mr < NEW0) v = *(const float4*)(kv_src_row(vc, vsp, h, mr) + c4);
    *(float4*)&vsf[p * 16 + (tid >> 4)][c4] = v;
  }
  __syncthreads();
#pragma unroll
  for (int e0 = 0; e0 < 2; ++e0) {
    const int e = tid + e0 * 256;
    const int d = e >> 3;
    const int ms = (e & 7) * 8;
    __hip_bfloat16 t[8];
#pragma unroll
    for (int j = 0; j < 8; ++j) t[j] = __float2bfloat16(vsf[ms + j][d]);
    *(uint4*)(Vt + ((size_t)h * HD + d) * MP + m0 + ms) = *(const uint4*)t;
  }
}

// ---------------------------------------------------------------------------
// MFMA flash attention partial, S token-stripes.
// Grid: 9 qtiles x 12 heads x S stripes, XCD-swizzled. Block: 4 waves,
// wave = 16 queries. Reg-staged prefetch of next tile; defer-max (THR=8);
// l via extra MFMA column (vts rows 64..79: row64=ones).
// ---------------------------------------------------------------------------
template <int S>
__global__ __launch_bounds__(256) void attn_partial(
    const __hip_bfloat16* __restrict__ Qb, const __hip_bfloat16* __restrict__ Kf,
    const __hip_bfloat16* __restrict__ Vt, float* __restrict__ Opart,
    float2* __restrict__ mlpart) {
  __shared__ __align__(16) __hip_bfloat16 ks[64][72];
  __shared__ __align__(16) __hip_bfloat16 vts[80][72];   // 64..79: l-column
  __shared__ __align__(16) __hip_bfloat16 pl[4][16][72];

  const int tid = threadIdx.x;
  const int w = tid >> 6, l = tid & 63, l15 = l & 15, lg = l >> 4;

  const int per_xcd = (9 * NH * S) / 8;
  const int i = blockIdx.x;
  const int work = (i & 7) * per_xcd + (i >> 3);
  const int h = work / (9 * S);
  const int rem = work - h * (9 * S);
  const int qt = rem / S;
  const int s = rem - qt * S;
  const int q0 = qt * 64 + w * 16;

  // init l-accumulator rows once (row 64 = 1.0, rows 65..79 = 0)
  for (int e = tid; e < 16 * 36; e += 256) {
    const int r = e / 36, cu = e - r * 36;
    ((unsigned int*)&vts[64 + r][0])[cu] = (r == 0) ? 0x3F803F80u : 0u;
  }

  bf16x8 qf[2];
  {
    const __hip_bfloat16* qp = Qb + ((size_t)h * NT + q0 + l15) * HD + 8 * lg;
    qf[0] = *(const bf16x8*)qp;
    qf[1] = *(const bf16x8*)(qp + 32);
  }

  f32x4 acc_o[4], acc_l = (f32x4){0.f, 0.f, 0.f, 0.f};
#pragma unroll
  for (int dt = 0; dt < 4; ++dt) acc_o[dt] = (f32x4){0.f, 0.f, 0.f, 0.f};
  float m_run[4] = {-1e30f, -1e30f, -1e30f, -1e30f};

  const __hip_bfloat16* Kh = Kf + (size_t)h * MP * HD;
  const __hip_bfloat16* Vth = Vt + (size_t)h * HD * MP;

  const int rr0 = tid >> 3, rr1 = (tid + 256) >> 3;
  const int c8 = (tid & 7) * 8;

  uint4 kr[2], vr[2];
  {  // prologue: stage tile t=s
    const int m0 = s * 64;
    kr[0] = *(const uint4*)(Kh + (size_t)(m0 + rr0) * HD + c8);
    kr[1] = *(const uint4*)(Kh + (size_t)(m0 + rr1) * HD + c8);
    vr[0] = *(const uint4*)(Vth + (size_t)rr0 * MP + m0 + c8);
    vr[1] = *(const uint4*)(Vth + (size_t)rr1 * MP + m0 + c8);
    *(uint4*)&ks[rr0][c8] = kr[0];
    *(uint4*)&ks[rr1][c8] = kr[1];
    *(uint4*)&vts[rr0][c8] = vr[0];
    *(uint4*)&vts[rr1][c8] = vr[1];
  }
  __syncthreads();

  for (int t = s; t < NTIL; t += S) {
    const int m0 = t * 64;
    const int tn = t + S;
    if (tn < NTIL) {  // prefetch next tile into regs (latency hides under compute)
      const int mn0 = tn * 64;
      kr[0] = *(const uint4*)(Kh + (size_t)(mn0 + rr0) * HD + c8);
      kr[1] = *(const uint4*)(Kh + (size_t)(mn0 + rr1) * HD + c8);
      vr[0] = *(const uint4*)(Vth + (size_t)rr0 * MP + mn0 + c8);
      vr[1] = *(const uint4*)(Vth + (size_t)rr1 * MP + mn0 + c8);
    }

    // QK^T
    f32x4 sc[4];
#pragma unroll
    for (int c = 0; c < 4; ++c) {
      const bf16x8 k0 = *(const bf16x8*)&ks[c * 16 + l15][8 * lg];
      const bf16x8 k1 = *(const bf16x8*)&ks[c * 16 + l15][32 + 8 * lg];
      f32x4 z = (f32x4){0.f, 0.f, 0.f, 0.f};
      z = __builtin_amdgcn_mfma_f32_16x16x32_bf16(qf[0], k0, z, 0, 0, 0);
      sc[c] = __builtin_amdgcn_mfma_f32_16x16x32_bf16(qf[1], k1, z, 0, 0, 0);
    }
    if (m0 + 64 > M_TOT) {
#pragma unroll
      for (int c = 0; c < 4; ++c)
        if (m0 + c * 16 + l15 >= M_TOT)
          sc[c] = (f32x4){-1e30f, -1e30f, -1e30f, -1e30f};
    }

    // tile row-max
    float mt[4];
#pragma unroll
    for (int r = 0; r < 4; ++r) {
      float v = fmaxf(fmaxf(sc[0][r], sc[1][r]), fmaxf(sc[2][r], sc[3][r]));
#pragma unroll
      for (int off = 8; off >= 1; off >>= 1) v = fmaxf(v, __shfl_xor(v, off));
      mt[r] = v;
    }
    // defer-max: rescale only if some row grew past m_run + 8
    const bool ok = (mt[0] <= m_run[0] + 8.f) && (mt[1] <= m_run[1] + 8.f) &&
                    (mt[2] <= m_run[2] + 8.f) && (mt[3] <= m_run[3] + 8.f);
    if (!__all(ok)) {
#pragma unroll
      for (int r = 0; r < 4; ++r) {
        const float mn = fmaxf(m_run[r], mt[r]);
        const float corr = __expf(m_run[r] - mn);
        m_run[r] = mn;
#pragma unroll
        for (int dt = 0; dt < 4; ++dt) acc_o[dt][r] *= corr;
        acc_l[r] *= corr;
      }
    }

    // P = exp(S - m_run) -> per-wave LDS (bf16)
#pragma unroll
    for (int c = 0; c < 4; ++c)
#pragma unroll
      for (int r = 0; r < 4; ++r)
        pl[w][4 * lg + r][16 * c + l15] =
            __float2bfloat16(__expf(sc[c][r] - m_run[r]));

    // PV + l-column
#pragma unroll
    for (int k2 = 0; k2 < 2; ++k2) {
      const bf16x8 pa = *(const bf16x8*)&pl[w][l15][32 * k2 + 8 * lg];
#pragma unroll
      for (int dt = 0; dt < 4; ++dt) {
        const bf16x8 vb = *(const bf16x8*)&vts[16 * dt + l15][32 * k2 + 8 * lg];
        acc_o[dt] = __builtin_amdgcn_mfma_f32_16x16x32_bf16(pa, vb, acc_o[dt], 0, 0, 0);
      }
      const bf16x8 vl = *(const bf16x8*)&vts[64 + l15][32 * k2 + 8 * lg];
      acc_l = __builtin_amdgcn_mfma_f32_16x16x32_bf16(pa, vl, acc_l, 0, 0, 0);
    }

    __syncthreads();
    if (tn < NTIL) {
      *(uint4*)&ks[rr0][c8] = kr[0];
      *(uint4*)&ks[rr1][c8] = kr[1];
      *(uint4*)&vts[rr0][c8] = vr[0];
      *(uint4*)&vts[rr1][c8] = vr[1];
      __syncthreads();
    }
  }

  float* Op = Opart + (((size_t)s * NH + h) * NT) * HD;
#pragma unroll
  for (int dt = 0; dt < 4; ++dt)
#pragma unroll
    for (int r = 0; r < 4; ++r)
      Op[(size_t)(q0 + 4 * lg + r) * HD + 16 * dt + l15] = acc_o[dt][r];
  if (l15 == 0) {
#pragma unroll
    for (int r = 0; r < 4; ++r)
      mlpart[((size_t)s * NH + h) * NT + q0 + 4 * lg + r] =
          make_float2(m_run[r], acc_l[r]);
  }
}

template <int S>
__global__ __launch_bounds__(256) void attn_merge(
    const float* __restrict__ Opart, const float2* __restrict__ mlpart,
    float* __restrict__ Ow) {
  const int idx = blockIdx.x * 256 + threadIdx.x;
  if (idx >= NH * NT * HD) return;
  const int d = idx & 63;
  const int hn = idx >> 6;
  const int n = hn % NT;
  const int h = hn / NT;
  float m[S], lv[S], M = -1e30f;
#pragma unroll
  for (int s = 0; s < S; ++s) {
    const float2 ml = mlpart[((size_t)s * NH + h) * NT + n];
    m[s] = ml.x; lv[s] = ml.y;
    M = fmaxf(M, m[s]);
  }
  float L = 0.f, O = 0.f;
#pragma unroll
  for (int s = 0; s < S; ++s) {
    const float e = __expf(m[s] - M);
    L += lv[s] * e;
    O += Opart[(((size_t)s * NH + h) * NT + n) * HD + d] * e;
  }
  Ow[(size_t)n * CC + h * HD + d] = O / L;
}

// ---------------------------------------------------------------------------
// fp32 proj GEMM (kept from round 2): out[m][c] = Ow[m,:] . proj_w[c,:] + b
// ---------------------------------------------------------------------------
__global__ __launch_bounds__(256) void gemm_proj(
    const float* __restrict__ A, const float* __restrict__ W,
    const float* __restrict__ bias, float* __restrict__ out_f) {
  __shared__ float xs[32][36];
  __shared__ float wsT[32][68];
  const int tid = threadIdx.x;
  const int tx = tid & 15, ty = tid >> 4;
  const int bm = blockIdx.y * 32, bn = blockIdx.x * 64;
  float acc[2][4] = {{0.f, 0.f, 0.f, 0.f}, {0.f, 0.f, 0.f, 0.f}};
  for (int k0 = 0; k0 < CC; k0 += 32) {
    {
      const int r = tid >> 3, kq = (tid & 7) << 2;
      *(float4*)&xs[r][kq] = *(const float4*)(A + (size_t)(bm + r) * CC + k0 + kq);
    }
#pragma unroll
    for (int e0 = 0; e0 < 2; ++e0) {
      const int e = tid + e0 * 256;
      const int r = e >> 3, kq = (e & 7) << 2;
      float4 v = *(const float4*)(W + (size_t)(bn + r) * CC + k0 + kq);
      wsT[kq + 0][r] = v.x; wsT[kq + 1][r] = v.y;
      wsT[kq + 2][r] = v.z; wsT[kq + 3][r] = v.w;
    }
    __syncthreads();
#pragma unroll
    for (int kk = 0; kk < 32; ++kk) {
      const float a0 = xs[ty * 2 + 0][kk];
      const float a1 = xs[ty * 2 + 1][kk];
      const float4 b = *(const float4*)&wsT[kk][tx * 4];
      acc[0][0] = fmaf(a0, b.x, acc[0][0]); acc[0][1] = fmaf(a0, b.y, acc[0][1]);
      acc[0][2] = fmaf(a0, b.z, acc[0][2]); acc[0][3] = fmaf(a0, b.w, acc[0][3]);
      acc[1][0] = fmaf(a1, b.x, acc[1][0]); acc[1][1] = fmaf(a1, b.y, acc[1][1]);
      acc[1][2] = fmaf(a1, b.z, acc[1][2]); acc[1][3] = fmaf(a1, b.w, acc[1][3]);
    }
    __syncthreads();
  }
#pragma unroll
  for (int i = 0; i < 2; ++i)
#pragma unroll
    for (int j = 0; j < 4; ++j) {
      const int m = bm + ty * 2 + i, c = bn + tx * 4 + j;
      out_f[(size_t)m * CC + c] = acc[i][j] + bias[c];
    }
}

// ---------------------------------------------------------------------------
extern "C" void kernel_launch(void* const* d_in, const int* in_sizes, int n_in,
                              void* d_out, int out_size, void* d_ws,
                              size_t ws_size, hipStream_t stream) {
  const float* x       = (const float*)d_in[0];
  const float* qkv_w   = (const float*)d_in[1];
  const float* qkv_b   = (const float*)d_in[2];
  const float* proj_w  = (const float*)d_in[3];
  const float* proj_b  = (const float*)d_in[4];
  const float* k_cache = (const float*)d_in[5];
  const float* v_cache = (const float*)d_in[6];
  const float* k_specl = (const float*)d_in[7];
  const float* v_specl = (const float*)d_in[8];
  float* out = (float*)d_out;

  const size_t qb_bytes = (size_t)NH * NT * HD * 2;      //    884,736
  const size_t kv_bytes = (size_t)NH * MP * HD * 2;      // 21,430,272
  const size_t xb_bytes = (size_t)NT * CC * 2;           //    884,736
  const size_t wb_bytes = (size_t)3 * CC * CC * 2;       //  3,538,944
  const size_t ow_bytes = (size_t)NT * CC * 4;           //  1,769,472

  auto layout = [&](int S, char*& qbp, char*& kfp, char*& vtp, char*& opp,
                    char*& mlp, char*& owp, char*& xbp, char*& wbp) -> size_t {
    const size_t op_bytes = (size_t)S * NH * NT * HD * 4;
    const size_t ml_bytes = (size_t)S * NH * NT * 8;
    char* ws = (char*)d_ws;
    qbp = ws;                       ws += qb_bytes;
    kfp = ws;                       ws += kv_bytes;
    vtp = ws;                       ws += kv_bytes;
    opp = ws;  xbp = opp; wbp = opp + xb_bytes;  // xb/wb alias under Opart
    ws += (op_bytes > xb_bytes + wb_bytes ? op_bytes : xb_bytes + wb_bytes);
    mlp = ws;                       ws += ml_bytes;
    owp = ws;                       ws += ow_bytes;
    return (size_t)(ws - (char*)d_ws);
  };

  char *qbp, *kfp, *vtp, *opp, *mlp, *owp, *xbp, *wbp;
  int S = 8;
  if (layout(8, qbp, kfp, vtp, opp, mlp, owp, xbp, wbp) > ws_size) S = 4;
  layout(S, qbp, kfp, vtp, opp, mlp, owp, xbp, wbp);

  __hip_bfloat16* Qb = (__hip_bfloat16*)qbp;
  __hip_bfloat16* Kf = (__hip_bfloat16*)kfp;
  __hip_bfloat16* Vt = (__hip_bfloat16*)vtp;
  float* Opart = (float*)opp;
  float2* mlpart = (float2*)mlp;
  float* Ow = (float*)owp;
  __hip_bfloat16* xb = (__hip_bfloat16*)xbp;
  __hip_bfloat16* wb = (__hip_bfloat16*)wbp;

  // 1) bf16 copies of x and qkv_w
  cvt_bf16<<<dim3((NT * CC / 8 + 255) / 256), 256, 0, stream>>>(x, xb, NT * CC / 8);
  cvt_bf16<<<dim3((3 * CC * CC / 8 + 255) / 256), 256, 0, stream>>>(
      qkv_w, wb, 3 * CC * CC / 8);
  // 2) gathers (before gemm: gemm fills [NEW0,M_TOT) afterwards)
  {
    const int totk = NH * NEW0 * 16;
    gather_k<<<dim3((totk + 255) / 256), 256, 0, stream>>>(k_cache, k_specl, Kf);
    gather_vt<<<dim3(MP / 64, NH), 256, 0, stream>>>(v_cache, v_specl, Vt);
  }
  // 3) QKV projection (MFMA) -> Qb, Kf tail, Vt tail
  gemm_qkv_mfma<<<dim3(36, 9), 256, 0, stream>>>(xb, wb, qkv_b, Qb, Kf, Vt);
  // 4) attention partials + merge
  if (S == 8) {
    attn_partial<8><<<dim3(9 * NH * 8), 256, 0, stream>>>(Qb, Kf, Vt, Opart, mlpart);
    attn_merge<8><<<dim3((NH * NT * HD + 255) / 256), 256, 0, stream>>>(Opart, mlpart, Ow);
  } else {
    attn_partial<4><<<dim3(9 * NH * 4), 256, 0, stream>>>(Qb, Kf, Vt, Opart, mlpart);
    attn_merge<4><<<dim3((NH * NT * HD + 255) / 256), 256, 0, stream>>>(Opart, mlpart, Ow);
  }
  // 5) output projection (fp32)
  gemm_proj<<<dim3(12, 18), 256, 0, stream>>>(Ow, proj_w, proj_b, out);
}

// Round 4
// 170.416 us; speedup vs baseline: 1.3545x; 1.3545x over previous
//
#include <hip/hip_runtime.h>
#include <hip/hip_bf16.h>

// Problem constants
#define NH    12      // heads
#define HD    64      // head dim
#define NT    576     // tokens (queries)
#define CC    768     // channels
#define M_TOT 13914   // total KV tokens per head (90 special + 72*192 cache)
#define MP    13952   // M padded to multiple of 64
#define NTIL  218     // MP / 64
#define NEW0  13338   // where the 576 new k/v tokens land in Kf/Vt

typedef short bf16x8 __attribute__((ext_vector_type(8)));
typedef float f32x4 __attribute__((ext_vector_type(4)));

// ---------------------------------------------------------------------------
// f32 -> bf16 bulk convert (8 elems/thread)
// ---------------------------------------------------------------------------
__global__ __launch_bounds__(256) void cvt_bf16(
    const float* __restrict__ src, __hip_bfloat16* __restrict__ dst, int n8) {
  const int i = blockIdx.x * 256 + threadIdx.x;
  if (i >= n8) return;
  const float4 a = ((const float4*)src)[2 * i];
  const float4 b = ((const float4*)src)[2 * i + 1];
  __hip_bfloat16 t[8];
  t[0] = __float2bfloat16(a.x); t[1] = __float2bfloat16(a.y);
  t[2] = __float2bfloat16(a.z); t[3] = __float2bfloat16(a.w);
  t[4] = __float2bfloat16(b.x); t[5] = __float2bfloat16(b.y);
  t[6] = __float2bfloat16(b.z); t[7] = __float2bfloat16(b.w);
  ((uint4*)dst)[i] = *(const uint4*)t;
}

// ---------------------------------------------------------------------------
// QKV projection via MFMA, no LDS (x and W are L2-resident bf16).
// ---------------------------------------------------------------------------
__global__ __launch_bounds__(256) void gemm_qkv_mfma(
    const __hip_bfloat16* __restrict__ xb, const __hip_bfloat16* __restrict__ wb,
    const float* __restrict__ bias, __hip_bfloat16* __restrict__ Qb,
    __hip_bfloat16* __restrict__ Kf, __hip_bfloat16* __restrict__ Vt) {
  const int tid = threadIdx.x;
  const int w = tid >> 6, l = tid & 63, l15 = l & 15, lg = l >> 4;
  const int n0 = blockIdx.x * 64;
  const int mw = blockIdx.y * 64 + w * 16;

  f32x4 acc[4];
#pragma unroll
  for (int nt = 0; nt < 4; ++nt) acc[nt] = (f32x4){0.f, 0.f, 0.f, 0.f};

  const __hip_bfloat16* arow = xb + (size_t)(mw + l15) * CC + 8 * lg;
#pragma unroll 4
  for (int k0 = 0; k0 < CC; k0 += 32) {
    const bf16x8 a = *(const bf16x8*)(arow + k0);
#pragma unroll
    for (int nt = 0; nt < 4; ++nt) {
      const bf16x8 b =
          *(const bf16x8*)(wb + (size_t)(n0 + nt * 16 + l15) * CC + k0 + 8 * lg);
      acc[nt] = __builtin_amdgcn_mfma_f32_16x16x32_bf16(a, b, acc[nt], 0, 0, 0);
    }
  }

#pragma unroll
  for (int nt = 0; nt < 4; ++nt) {
    const int c = n0 + nt * 16 + l15;
    const int which = c / CC;  // 0=q 1=k 2=v
    const int rem = c - which * CC;
    const int hh = rem >> 6;
    const int dd = rem & 63;
    const float bc = bias[c];
#pragma unroll
    for (int r = 0; r < 4; ++r) {
      const int m = mw + 4 * lg + r;
      const float v = acc[nt][r] + bc;
      if (which == 0) {
        Qb[((size_t)hh * NT + m) * HD + dd] = __float2bfloat16(v * 0.125f);
      } else if (which == 1) {
        Kf[((size_t)hh * MP + NEW0 + m) * HD + dd] = __float2bfloat16(v);
      } else {
        Vt[((size_t)hh * HD + dd) * MP + NEW0 + m] = __float2bfloat16(v);
      }
    }
  }
}

// ---------------------------------------------------------------------------
// Token map per head (verified):
//   [0,72) special | [72,90) frames 8..10 tok 0..5 | [90,1626) frames 0..7
//   [1626,13338) frames 11..71 | [13338,13914) new (from qkv gemm)
// ---------------------------------------------------------------------------
__device__ __forceinline__ const float* kv_src_row(
    const float* __restrict__ cache, const float* __restrict__ special,
    int h, int m) {
  if (m < 72) return special + ((size_t)h * 72 + m) * HD;
  if (m < 90) {
    const int j = m - 72;
    return cache + (((size_t)h * 72 + 8 + j / 6) * 192 + (j % 6)) * HD;
  }
  if (m < 1626) return cache + ((size_t)h * 13824 + (m - 90)) * HD;
  return cache + ((size_t)h * 13824 + 2112 + (m - 1626)) * HD;
}

__global__ __launch_bounds__(256) void gather_k(
    const float* __restrict__ kc, const float* __restrict__ ksp,
    __hip_bfloat16* __restrict__ Kf) {
  const int idx = blockIdx.x * 256 + threadIdx.x;
  const int per_h = NEW0 * 16;
  if (idx >= NH * per_h) return;
  const int h = idx / per_h;
  const int r = idx - h * per_h;
  const int m = r >> 4;
  const int dq = (r & 15) << 2;
  const float4 v = *(const float4*)(kv_src_row(kc, ksp, h, m) + dq);
  __hip_bfloat162* dst = (__hip_bfloat162*)(Kf + ((size_t)h * MP + m) * HD + dq);
  __hip_bfloat162 a, b;
  a.x = __float2bfloat16(v.x); a.y = __float2bfloat16(v.y);
  b.x = __float2bfloat16(v.z); b.y = __float2bfloat16(v.w);
  dst[0] = a; dst[1] = b;
}

// V transpose gather via LDS: coalesced reads AND writes.
__global__ __launch_bounds__(256) void gather_vt(
    const float* __restrict__ vc, const float* __restrict__ vsp,
    __hip_bfloat16* __restrict__ Vt) {
  __shared__ float vsf[64][68];
  const int h = blockIdx.y;
  const int m0 = blockIdx.x * 64;
  const int tid = threadIdx.x;
#pragma unroll
  for (int p = 0; p < 4; ++p) {
    const int mr = m0 + p * 16 + (tid >> 4);
    const int c4 = (tid & 15) * 4;
    float4 v = make_float4(0.f, 0.f, 0.f, 0.f);
    if (mr < NEW0) v = *(const float4*)(kv_src_row(vc, vsp, h, mr) + c4);
    *(float4*)&vsf[p * 16 + (tid >> 4)][c4] = v;
  }
  __syncthreads();
#pragma unroll
  for (int e0 = 0; e0 < 2; ++e0) {
    const int e = tid + e0 * 256;
    const int d = e >> 3;
    const int ms = (e & 7) * 8;
    __hip_bfloat16 t[8];
#pragma unroll
    for (int j = 0; j < 8; ++j) t[j] = __float2bfloat16(vsf[ms + j][d]);
    *(uint4*)(Vt + ((size_t)h * HD + d) * MP + m0 + ms) = *(const uint4*)t;
  }
}

// ---------------------------------------------------------------------------
// MFMA flash attention partial, S token-stripes.
// Grid: 9 qtiles x 12 heads x S stripes, XCD-swizzled. Block: 4 waves,
// wave = 16 queries. Direct LDS staging (NO reg prefetch — round-3's spilled
// to scratch: 212 MB HBM writes). launch_bounds(256,4) caps regalloc at 128
// VGPR so the compiler doesn't squeeze to 8 waves/EU and spill.
// defer-max (THR=8); l via extra MFMA column (vts rows 64..79, row64=ones).
// ---------------------------------------------------------------------------
template <int S>
__global__ __launch_bounds__(256, 4) void attn_partial(
    const __hip_bfloat16* __restrict__ Qb, const __hip_bfloat16* __restrict__ Kf,
    const __hip_bfloat16* __restrict__ Vt, float* __restrict__ Opart,
    float2* __restrict__ mlpart) {
  __shared__ __align__(16) __hip_bfloat16 ks[64][72];
  __shared__ __align__(16) __hip_bfloat16 vts[80][72];   // 64..79: l-column
  __shared__ __align__(16) __hip_bfloat16 pl[4][16][72];

  const int tid = threadIdx.x;
  const int w = tid >> 6, l = tid & 63, l15 = l & 15, lg = l >> 4;

  const int per_xcd = (9 * NH * S) / 8;
  const int i = blockIdx.x;
  const int work = (i & 7) * per_xcd + (i >> 3);
  const int h = work / (9 * S);
  const int rem = work - h * (9 * S);
  const int qt = rem / S;
  const int s = rem - qt * S;
  const int q0 = qt * 64 + w * 16;

  // init l-accumulator rows once (row 64 = 1.0, rows 65..79 = 0)
  for (int e = tid; e < 16 * 36; e += 256) {
    const int r = e / 36, cu = e - r * 36;
    ((unsigned int*)&vts[64 + r][0])[cu] = (r == 0) ? 0x3F803F80u : 0u;
  }

  bf16x8 qf[2];
  {
    const __hip_bfloat16* qp = Qb + ((size_t)h * NT + q0 + l15) * HD + 8 * lg;
    qf[0] = *(const bf16x8*)qp;
    qf[1] = *(const bf16x8*)(qp + 32);
  }

  f32x4 acc_o[4], acc_l = (f32x4){0.f, 0.f, 0.f, 0.f};
#pragma unroll
  for (int dt = 0; dt < 4; ++dt) acc_o[dt] = (f32x4){0.f, 0.f, 0.f, 0.f};
  float m_run[4] = {-1e30f, -1e30f, -1e30f, -1e30f};

  const __hip_bfloat16* Kh = Kf + (size_t)h * MP * HD;
  const __hip_bfloat16* Vth = Vt + (size_t)h * HD * MP;

  const int rr0 = tid >> 3, rr1 = (tid + 256) >> 3;
  const int c8 = (tid & 7) * 8;

  for (int t = s; t < NTIL; t += S) {
    const int m0 = t * 64;
    // stage K [64 tok][64 d] and Vt [64 d][64 tok] directly into LDS
    *(uint4*)&ks[rr0][c8] = *(const uint4*)(Kh + (size_t)(m0 + rr0) * HD + c8);
    *(uint4*)&ks[rr1][c8] = *(const uint4*)(Kh + (size_t)(m0 + rr1) * HD + c8);
    *(uint4*)&vts[rr0][c8] = *(const uint4*)(Vth + (size_t)rr0 * MP + m0 + c8);
    *(uint4*)&vts[rr1][c8] = *(const uint4*)(Vth + (size_t)rr1 * MP + m0 + c8);
    __syncthreads();

    // QK^T
    f32x4 sc[4];
#pragma unroll
    for (int c = 0; c < 4; ++c) {
      const bf16x8 k0 = *(const bf16x8*)&ks[c * 16 + l15][8 * lg];
      const bf16x8 k1 = *(const bf16x8*)&ks[c * 16 + l15][32 + 8 * lg];
      f32x4 z = (f32x4){0.f, 0.f, 0.f, 0.f};
      z = __builtin_amdgcn_mfma_f32_16x16x32_bf16(qf[0], k0, z, 0, 0, 0);
      sc[c] = __builtin_amdgcn_mfma_f32_16x16x32_bf16(qf[1], k1, z, 0, 0, 0);
    }
    if (m0 + 64 > M_TOT) {
#pragma unroll
      for (int c = 0; c < 4; ++c)
        if (m0 + c * 16 + l15 >= M_TOT)
          sc[c] = (f32x4){-1e30f, -1e30f, -1e30f, -1e30f};
    }

    // tile row-max
    float mt[4];
#pragma unroll
    for (int r = 0; r < 4; ++r) {
      float v = fmaxf(fmaxf(sc[0][r], sc[1][r]), fmaxf(sc[2][r], sc[3][r]));
#pragma unroll
      for (int off = 8; off >= 1; off >>= 1) v = fmaxf(v, __shfl_xor(v, off));
      mt[r] = v;
    }
    // defer-max: rescale only if some row grew past m_run + 8
    const bool ok = (mt[0] <= m_run[0] + 8.f) && (mt[1] <= m_run[1] + 8.f) &&
                    (mt[2] <= m_run[2] + 8.f) && (mt[3] <= m_run[3] + 8.f);
    if (!__all(ok)) {
#pragma unroll
      for (int r = 0; r < 4; ++r) {
        const float mn = fmaxf(m_run[r], mt[r]);
        const float corr = __expf(m_run[r] - mn);
        m_run[r] = mn;
#pragma unroll
        for (int dt = 0; dt < 4; ++dt) acc_o[dt][r] *= corr;
        acc_l[r] *= corr;
      }
    }

    // P = exp(S - m_run) -> per-wave LDS (bf16)
#pragma unroll
    for (int c = 0; c < 4; ++c)
#pragma unroll
      for (int r = 0; r < 4; ++r)
        pl[w][4 * lg + r][16 * c + l15] =
            __float2bfloat16(__expf(sc[c][r] - m_run[r]));

    // PV + l-column
#pragma unroll
    for (int k2 = 0; k2 < 2; ++k2) {
      const bf16x8 pa = *(const bf16x8*)&pl[w][l15][32 * k2 + 8 * lg];
#pragma unroll
      for (int dt = 0; dt < 4; ++dt) {
        const bf16x8 vb = *(const bf16x8*)&vts[16 * dt + l15][32 * k2 + 8 * lg];
        acc_o[dt] = __builtin_amdgcn_mfma_f32_16x16x32_bf16(pa, vb, acc_o[dt], 0, 0, 0);
      }
      const bf16x8 vl = *(const bf16x8*)&vts[64 + l15][32 * k2 + 8 * lg];
      acc_l = __builtin_amdgcn_mfma_f32_16x16x32_bf16(pa, vl, acc_l, 0, 0, 0);
    }
    __syncthreads();
  }

  float* Op = Opart + (((size_t)s * NH + h) * NT) * HD;
#pragma unroll
  for (int dt = 0; dt < 4; ++dt)
#pragma unroll
    for (int r = 0; r < 4; ++r)
      Op[(size_t)(q0 + 4 * lg + r) * HD + 16 * dt + l15] = acc_o[dt][r];
  if (l15 == 0) {
#pragma unroll
    for (int r = 0; r < 4; ++r)
      mlpart[((size_t)s * NH + h) * NT + q0 + 4 * lg + r] =
          make_float2(m_run[r], acc_l[r]);
  }
}

template <int S>
__global__ __launch_bounds__(256) void attn_merge(
    const float* __restrict__ Opart, const float2* __restrict__ mlpart,
    float* __restrict__ Ow) {
  const int idx = blockIdx.x * 256 + threadIdx.x;
  if (idx >= NH * NT * HD) return;
  const int d = idx & 63;
  const int hn = idx >> 6;
  const int n = hn % NT;
  const int h = hn / NT;
  float M = -1e30f;
  float m[S], lv[S];
#pragma unroll
  for (int s = 0; s < S; ++s) {
    const float2 ml = mlpart[((size_t)s * NH + h) * NT + n];
    m[s] = ml.x; lv[s] = ml.y;
    M = fmaxf(M, m[s]);
  }
  float L = 0.f, O = 0.f;
#pragma unroll
  for (int s = 0; s < S; ++s) {
    const float e = __expf(m[s] - M);
    L += lv[s] * e;
    O += Opart[(((size_t)s * NH + h) * NT + n) * HD + d] * e;
  }
  Ow[(size_t)n * CC + h * HD + d] = O / L;
}

// ---------------------------------------------------------------------------
// fp32 proj GEMM: out[m][c] = Ow[m,:] . proj_w[c,:] + b
// ---------------------------------------------------------------------------
__global__ __launch_bounds__(256) void gemm_proj(
    const float* __restrict__ A, const float* __restrict__ W,
    const float* __restrict__ bias, float* __restrict__ out_f) {
  __shared__ float xs[32][36];
  __shared__ float wsT[32][68];
  const int tid = threadIdx.x;
  const int tx = tid & 15, ty = tid >> 4;
  const int bm = blockIdx.y * 32, bn = blockIdx.x * 64;
  float acc[2][4] = {{0.f, 0.f, 0.f, 0.f}, {0.f, 0.f, 0.f, 0.f}};
  for (int k0 = 0; k0 < CC; k0 += 32) {
    {
      const int r = tid >> 3, kq = (tid & 7) << 2;
      *(float4*)&xs[r][kq] = *(const float4*)(A + (size_t)(bm + r) * CC + k0 + kq);
    }
#pragma unroll
    for (int e0 = 0; e0 < 2; ++e0) {
      const int e = tid + e0 * 256;
      const int r = e >> 3, kq = (e & 7) << 2;
      float4 v = *(const float4*)(W + (size_t)(bn + r) * CC + k0 + kq);
      wsT[kq + 0][r] = v.x; wsT[kq + 1][r] = v.y;
      wsT[kq + 2][r] = v.z; wsT[kq + 3][r] = v.w;
    }
    __syncthreads();
#pragma unroll
    for (int kk = 0; kk < 32; ++kk) {
      const float a0 = xs[ty * 2 + 0][kk];
      const float a1 = xs[ty * 2 + 1][kk];
      const float4 b = *(const float4*)&wsT[kk][tx * 4];
      acc[0][0] = fmaf(a0, b.x, acc[0][0]); acc[0][1] = fmaf(a0, b.y, acc[0][1]);
      acc[0][2] = fmaf(a0, b.z, acc[0][2]); acc[0][3] = fmaf(a0, b.w, acc[0][3]);
      acc[1][0] = fmaf(a1, b.x, acc[1][0]); acc[1][1] = fmaf(a1, b.y, acc[1][1]);
      acc[1][2] = fmaf(a1, b.z, acc[1][2]); acc[1][3] = fmaf(a1, b.w, acc[1][3]);
    }
    __syncthreads();
  }
#pragma unroll
  for (int i = 0; i < 2; ++i)
#pragma unroll
    for (int j = 0; j < 4; ++j) {
      const int m = bm + ty * 2 + i, c = bn + tx * 4 + j;
      out_f[(size_t)m * CC + c] = acc[i][j] + bias[c];
    }
}

// ---------------------------------------------------------------------------
extern "C" void kernel_launch(void* const* d_in, const int* in_sizes, int n_in,
                              void* d_out, int out_size, void* d_ws,
                              size_t ws_size, hipStream_t stream) {
  const float* x       = (const float*)d_in[0];
  const float* qkv_w   = (const float*)d_in[1];
  const float* qkv_b   = (const float*)d_in[2];
  const float* proj_w  = (const float*)d_in[3];
  const float* proj_b  = (const float*)d_in[4];
  const float* k_cache = (const float*)d_in[5];
  const float* v_cache = (const float*)d_in[6];
  const float* k_specl = (const float*)d_in[7];
  const float* v_specl = (const float*)d_in[8];
  float* out = (float*)d_out;

  const size_t qb_bytes = (size_t)NH * NT * HD * 2;      //    884,736
  const size_t kv_bytes = (size_t)NH * MP * HD * 2;      // 21,430,272
  const size_t xb_bytes = (size_t)NT * CC * 2;           //    884,736
  const size_t wb_bytes = (size_t)3 * CC * CC * 2;       //  3,538,944
  const size_t ow_bytes = (size_t)NT * CC * 4;           //  1,769,472

  auto layout = [&](int S, char*& qbp, char*& kfp, char*& vtp, char*& opp,
                    char*& mlp, char*& owp, char*& xbp, char*& wbp) -> size_t {
    const size_t op_bytes = (size_t)S * NH * NT * HD * 4;
    const size_t ml_bytes = (size_t)S * NH * NT * 8;
    char* ws = (char*)d_ws;
    qbp = ws;                       ws += qb_bytes;
    kfp = ws;                       ws += kv_bytes;
    vtp = ws;                       ws += kv_bytes;
    opp = ws;  xbp = opp; wbp = opp + xb_bytes;  // xb/wb alias under Opart
    ws += (op_bytes > xb_bytes + wb_bytes ? op_bytes : xb_bytes + wb_bytes);
    mlp = ws;                       ws += ml_bytes;
    owp = ws;                       ws += ow_bytes;
    return (size_t)(ws - (char*)d_ws);
  };

  char *qbp, *kfp, *vtp, *opp, *mlp, *owp, *xbp, *wbp;
  int S = 16;
  if (layout(16, qbp, kfp, vtp, opp, mlp, owp, xbp, wbp) > ws_size) S = 8;
  if (S == 8 && layout(8, qbp, kfp, vtp, opp, mlp, owp, xbp, wbp) > ws_size) S = 4;
  layout(S, qbp, kfp, vtp, opp, mlp, owp, xbp, wbp);

  __hip_bfloat16* Qb = (__hip_bfloat16*)qbp;
  __hip_bfloat16* Kf = (__hip_bfloat16*)kfp;
  __hip_bfloat16* Vt = (__hip_bfloat16*)vtp;
  float* Opart = (float*)opp;
  float2* mlpart = (float2*)mlp;
  float* Ow = (float*)owp;
  __hip_bfloat16* xb = (__hip_bfloat16*)xbp;
  __hip_bfloat16* wb = (__hip_bfloat16*)wbp;

  // 1) bf16 copies of x and qkv_w
  cvt_bf16<<<dim3((NT * CC / 8 + 255) / 256), 256, 0, stream>>>(x, xb, NT * CC / 8);
  cvt_bf16<<<dim3((3 * CC * CC / 8 + 255) / 256), 256, 0, stream>>>(
      qkv_w, wb, 3 * CC * CC / 8);
  // 2) gathers (before gemm: gemm fills [NEW0,M_TOT) afterwards)
  {
    const int totk = NH * NEW0 * 16;
    gather_k<<<dim3((totk + 255) / 256), 256, 0, stream>>>(k_cache, k_specl, Kf);
    gather_vt<<<dim3(MP / 64, NH), 256, 0, stream>>>(v_cache, v_specl, Vt);
  }
  // 3) QKV projection (MFMA) -> Qb, Kf tail, Vt tail
  gemm_qkv_mfma<<<dim3(36, 9), 256, 0, stream>>>(xb, wb, qkv_b, Qb, Kf, Vt);
  // 4) attention partials + merge
  if (S == 16) {
    attn_partial<16><<<dim3(9 * NH * 16), 256, 0, stream>>>(Qb, Kf, Vt, Opart, mlpart);
    attn_merge<16><<<dim3((NH * NT * HD + 255) / 256), 256, 0, stream>>>(Opart, mlpart, Ow);
  } else if (S == 8) {
    attn_partial<8><<<dim3(9 * NH * 8), 256, 0, stream>>>(Qb, Kf, Vt, Opart, mlpart);
    attn_merge<8><<<dim3((NH * NT * HD + 255) / 256), 256, 0, stream>>>(Opart, mlpart, Ow);
  } else {
    attn_partial<4><<<dim3(9 * NH * 4), 256, 0, stream>>>(Qb, Kf, Vt, Opart, mlpart);
    attn_merge<4><<<dim3((NH * NT * HD + 255) / 256), 256, 0, stream>>>(Opart, mlpart, Ow);
  }
  // 5) output projection (fp32)
  gemm_proj<<<dim3(12, 18), 256, 0, stream>>>(Ow, proj_w, proj_b, out);
}

// Round 5
// 126.725 us; speedup vs baseline: 1.8214x; 1.3448x over previous
//
#include <hip/hip_runtime.h>
#include <hip/hip_bf16.h>

// Problem constants
#define NH    12      // heads
#define HD    64      // head dim
#define NT    576     // tokens (queries)
#define CC    768     // channels
#define M_TOT 13914   // total KV tokens per head (90 special + 72*192 cache)
#define MP    13952   // M padded to multiple of 64
#define NTIL  218     // MP / 64
#define NEW0  13338   // where the 576 new k/v tokens land in Kf/Vt
#define SSTR  16      // KV stripes for attention

typedef short bf16x8 __attribute__((ext_vector_type(8)));
typedef float f32x4 __attribute__((ext_vector_type(4)));
typedef float f32x16 __attribute__((ext_vector_type(16)));

__device__ __forceinline__ unsigned pk2(float a, float b) {
  __hip_bfloat162 h = __float22bfloat162_rn(make_float2(a, b));
  return *(unsigned*)&h;
}

// ---------------------------------------------------------------------------
// Kernel A: f32 -> bf16 copies of x and qkv_w (fused)
// ---------------------------------------------------------------------------
__global__ __launch_bounds__(256) void cvt_all(
    const float* __restrict__ x, const float* __restrict__ wsrc,
    __hip_bfloat16* __restrict__ xb, __hip_bfloat16* __restrict__ wb) {
  const int nx8 = NT * CC / 8;        // 55296
  const int nw8 = 3 * CC * CC / 8;    // 221184
  int i = blockIdx.x * 256 + threadIdx.x;
  const float* src;
  __hip_bfloat16* dst;
  int j;
  if (i < nx8) { src = x; dst = xb; j = i; }
  else { j = i - nx8; if (j >= nw8) return; src = wsrc; dst = wb; }
  const float4 a = ((const float4*)src)[2 * j];
  const float4 b = ((const float4*)src)[2 * j + 1];
  __hip_bfloat16 t[8];
  t[0] = __float2bfloat16(a.x); t[1] = __float2bfloat16(a.y);
  t[2] = __float2bfloat16(a.z); t[3] = __float2bfloat16(a.w);
  t[4] = __float2bfloat16(b.x); t[5] = __float2bfloat16(b.y);
  t[6] = __float2bfloat16(b.z); t[7] = __float2bfloat16(b.w);
  ((uint4*)dst)[j] = *(const uint4*)t;
}

// ---------------------------------------------------------------------------
// Token map per head (verified):
//   [0,72) special | [72,90) frames 8..10 tok 0..5 | [90,1626) frames 0..7
//   [1626,13338) frames 11..71 | [13338,13914) new (from qkv gemm)
// ---------------------------------------------------------------------------
__device__ __forceinline__ const float* kv_src_row(
    const float* __restrict__ cache, const float* __restrict__ special,
    int h, int m) {
  if (m < 72) return special + ((size_t)h * 72 + m) * HD;
  if (m < 90) {
    const int j = m - 72;
    return cache + (((size_t)h * 72 + 8 + j / 6) * 192 + (j % 6)) * HD;
  }
  if (m < 1626) return cache + ((size_t)h * 13824 + (m - 90)) * HD;
  return cache + ((size_t)h * 13824 + 2112 + (m - 1626)) * HD;
}

// ---------------------------------------------------------------------------
// Kernel B (fused, 3 roles by blockIdx):
//   [0,324)        qkv MFMA gemm -> Qb, Kf[NEW0+m], Vt[d][NEW0+m]
//   [324,2940)     V transpose gather (m < NEW0 only; no overlap with gemm)
//   [2940,12944)   K gather (m < NEW0)
// ---------------------------------------------------------------------------
#define GEMM_BLKS 324
#define VT_BLKS   2616   // 218 * 12
#define KB_BLKS   10004  // ceil(12*13338*16 / 256)

__global__ __launch_bounds__(256) void qkv_and_gather(
    const __hip_bfloat16* __restrict__ xb, const __hip_bfloat16* __restrict__ wb,
    const float* __restrict__ bias, __hip_bfloat16* __restrict__ Qb,
    __hip_bfloat16* __restrict__ Kf, __hip_bfloat16* __restrict__ Vt,
    const float* __restrict__ kc, const float* __restrict__ ksp,
    const float* __restrict__ vc, const float* __restrict__ vsp) {
  __shared__ float vsf[64][68];
  const int bx = blockIdx.x;
  const int tid = threadIdx.x;

  if (bx < GEMM_BLKS) {
    // ---- QKV projection via MFMA (no LDS; xb/wb are L2-resident) ----
    const int w = tid >> 6, l = tid & 63, l15 = l & 15, lg = l >> 4;
    const int n0 = (bx % 36) * 64;
    const int mw = (bx / 36) * 64 + w * 16;

    f32x4 acc[4];
#pragma unroll
    for (int nt = 0; nt < 4; ++nt) acc[nt] = (f32x4){0.f, 0.f, 0.f, 0.f};

    const __hip_bfloat16* arow = xb + (size_t)(mw + l15) * CC + 8 * lg;
#pragma unroll 4
    for (int k0 = 0; k0 < CC; k0 += 32) {
      const bf16x8 a = *(const bf16x8*)(arow + k0);
#pragma unroll
      for (int nt = 0; nt < 4; ++nt) {
        const bf16x8 b =
            *(const bf16x8*)(wb + (size_t)(n0 + nt * 16 + l15) * CC + k0 + 8 * lg);
        acc[nt] = __builtin_amdgcn_mfma_f32_16x16x32_bf16(a, b, acc[nt], 0, 0, 0);
      }
    }
#pragma unroll
    for (int nt = 0; nt < 4; ++nt) {
      const int c = n0 + nt * 16 + l15;
      const int which = c / CC;
      const int rem = c - which * CC;
      const int hh = rem >> 6;
      const int dd = rem & 63;
      const float bc = bias[c];
#pragma unroll
      for (int r = 0; r < 4; ++r) {
        const int m = mw + 4 * lg + r;
        const float v = acc[nt][r] + bc;
        if (which == 0) {
          Qb[((size_t)hh * NT + m) * HD + dd] = __float2bfloat16(v * 0.125f);
        } else if (which == 1) {
          Kf[((size_t)hh * MP + NEW0 + m) * HD + dd] = __float2bfloat16(v);
        } else {
          Vt[((size_t)hh * HD + dd) * MP + NEW0 + m] = __float2bfloat16(v);
        }
      }
    }
  } else if (bx < GEMM_BLKS + VT_BLKS) {
    // ---- V transpose gather via LDS (writes only m < NEW0) ----
    const int tv = bx - GEMM_BLKS;
    const int m0 = (tv % 218) * 64;
    const int h = tv / 218;
    if (m0 >= NEW0) return;
#pragma unroll
    for (int p = 0; p < 4; ++p) {
      const int mr = m0 + p * 16 + (tid >> 4);
      const int c4 = (tid & 15) * 4;
      float4 v = make_float4(0.f, 0.f, 0.f, 0.f);
      if (mr < NEW0) v = *(const float4*)(kv_src_row(vc, vsp, h, mr) + c4);
      *(float4*)&vsf[p * 16 + (tid >> 4)][c4] = v;
    }
    __syncthreads();
#pragma unroll
    for (int e0 = 0; e0 < 2; ++e0) {
      const int e = tid + e0 * 256;
      const int d = e >> 3;
      const int ms = (e & 7) * 8;
      __hip_bfloat16 t[8];
#pragma unroll
      for (int j = 0; j < 8; ++j) t[j] = __float2bfloat16(vsf[ms + j][d]);
      __hip_bfloat16* dst = Vt + ((size_t)h * HD + d) * MP + m0 + ms;
      if (m0 + ms + 8 <= NEW0) {
        *(uint4*)dst = *(const uint4*)t;
      } else {
#pragma unroll
        for (int j = 0; j < 8; ++j)
          if (m0 + ms + j < NEW0) dst[j] = t[j];
      }
    }
  } else {
    // ---- K gather ----
    const int idx = (bx - GEMM_BLKS - VT_BLKS) * 256 + tid;
    const int per_h = NEW0 * 16;
    if (idx >= NH * per_h) return;
    const int h = idx / per_h;
    const int r = idx - h * per_h;
    const int m = r >> 4;
    const int dq = (r & 15) << 2;
    const float4 v = *(const float4*)(kv_src_row(kc, ksp, h, m) + dq);
    __hip_bfloat162* dst = (__hip_bfloat162*)(Kf + ((size_t)h * MP + m) * HD + dq);
    __hip_bfloat162 a, b;
    a.x = __float2bfloat16(v.x); a.y = __float2bfloat16(v.y);
    b.x = __float2bfloat16(v.z); b.y = __float2bfloat16(v.w);
    dst[0] = a; dst[1] = b;
  }
}

// ---------------------------------------------------------------------------
// MFMA flash attention partial — swapped-QK 32x32 structure.
// Grid: 5 qtiles(128) x 12 heads x 16 stripes = 960 blocks, XCD-swizzled
// (consecutive works share (h,stripe) => same KV stream in L2).
// Block: 4 waves, each owning 32 queries (query = MFMA column = lane&31).
// QK^T: D[tok][q] = mfma(K_frag, Q_frag) — lane holds 32 scores for its own
// query; softmax fully in-register (+1 shfl_xor(32) for the other 32 toks).
// P: cvt to bf16 in-register; B-frags assembled via 4 shfl_xor(32)/slice.
// PV: D[d][q] = mfma(V^T_frag, P_frag) — O stays per-lane for own query.
// K/V LDS tiles XOR-swizzled (byte ^= (row&7)<<4, stride 64) => uniform-8
// bank access on all b128 reads/writes.
// ---------------------------------------------------------------------------
__global__ __launch_bounds__(256, 4) void attn_partial(
    const __hip_bfloat16* __restrict__ Qb, const __hip_bfloat16* __restrict__ Kf,
    const __hip_bfloat16* __restrict__ Vt, float* __restrict__ Opart,
    float2* __restrict__ mlpart) {
  __shared__ __align__(16) char lds[16384];
  char* ksb = lds;          // K tile [tok][d]  (swizzled)
  char* vtb = lds + 8192;   // V^T tile [d][tok] (swizzled)

  const int tid = threadIdx.x;
  const int w = tid >> 6, l = tid & 63;
  const int l31 = l & 31, hi = l >> 5;

  const int i = blockIdx.x;
  const int work = (i & 7) * 120 + (i >> 3);
  const int qt = work % 5;
  const int hs = work / 5;
  const int h = hs % NH;
  const int strip = hs / NH;

  const int qrow = qt * 128 + w * 32 + l31;
  const int qrc = qrow < NT ? qrow : NT - 1;

  // Q B-fragments: qreg[s] = Q[q][16s + 8hi .. +8]
  bf16x8 qreg[4];
  {
    const __hip_bfloat16* qp = Qb + ((size_t)h * NT + qrc) * HD + 8 * hi;
#pragma unroll
    for (int s4 = 0; s4 < 4; ++s4) qreg[s4] = *(const bf16x8*)(qp + 16 * s4);
  }

  f32x16 oacc0, oacc1;  // O[d = crow(r,hi) + 32*dh][own q]
#pragma unroll
  for (int r = 0; r < 16; ++r) { oacc0[r] = 0.f; oacc1[r] = 0.f; }
  float m_run = -1e30f, l_run = 0.f;

  const __hip_bfloat16* Kh = Kf + (size_t)h * MP * HD;
  const __hip_bfloat16* Vth = Vt + (size_t)h * HD * MP;

  for (int t = strip; t < NTIL; t += SSTR) {
    const int m0 = t * 64;
    // ---- stage K and V^T tiles (swizzled) ----
#pragma unroll
    for (int e = 0; e < 2; ++e) {
      const int c = tid + 256 * e;
      const int row = c >> 3, p = c & 7;
      const unsigned off = ((unsigned)((row << 7) | (p << 4))) ^ ((row & 7) << 4);
      const uint4 kd = *(const uint4*)(Kh + (size_t)(m0 + row) * HD + p * 8);
      const uint4 vd = *(const uint4*)(Vth + (size_t)row * MP + m0 + p * 8);
      *(uint4*)(ksb + off) = kd;
      *(uint4*)(vtb + off) = vd;
    }
    __syncthreads();

    // ---- QK^T: sc0 = toks 0..31, sc1 = toks 32..63 (for own query) ----
    f32x16 sc0, sc1;
#pragma unroll
    for (int r = 0; r < 16; ++r) { sc0[r] = 0.f; sc1[r] = 0.f; }
#pragma unroll
    for (int s4 = 0; s4 < 4; ++s4) {
      const int cb = 32 * s4 + 16 * hi;
      const unsigned o0 = ((unsigned)((l31 << 7) | cb)) ^ ((l31 & 7) << 4);
      const unsigned o1 = ((unsigned)(((l31 + 32) << 7) | cb)) ^ ((l31 & 7) << 4);
      const bf16x8 a0 = *(const bf16x8*)(ksb + o0);
      const bf16x8 a1 = *(const bf16x8*)(ksb + o1);
      sc0 = __builtin_amdgcn_mfma_f32_32x32x16_bf16(a0, qreg[s4], sc0, 0, 0, 0);
      sc1 = __builtin_amdgcn_mfma_f32_32x32x16_bf16(a1, qreg[s4], sc1, 0, 0, 0);
    }

    // mask pad tokens (last tile only); lane's tok = crow(r,hi)=(r&3)+8(r>>2)+4hi
    if (m0 + 64 > M_TOT) {
#pragma unroll
      for (int r = 0; r < 16; ++r) {
        const int base = (r & 3) + 8 * (r >> 2) + 4 * hi;
        if (m0 + base >= M_TOT) sc0[r] = -1e30f;
        if (m0 + 32 + base >= M_TOT) sc1[r] = -1e30f;
      }
    }

    // ---- in-register softmax for own query ----
    float mt = sc0[0];
#pragma unroll
    for (int r = 1; r < 16; ++r) mt = fmaxf(mt, sc0[r]);
#pragma unroll
    for (int r = 0; r < 16; ++r) mt = fmaxf(mt, sc1[r]);
    mt = fmaxf(mt, __shfl_xor(mt, 32));

    // defer-max (THR=8): rescale only when some row grew past m_run+8
    if (__any(mt > m_run + 8.f)) {
      const float mn = fmaxf(m_run, mt);
      const float corr = __expf(m_run - mn);
      m_run = mn;
      l_run *= corr;
#pragma unroll
      for (int r = 0; r < 16; ++r) { oacc0[r] *= corr; oacc1[r] *= corr; }
    }

    // exp + pack to bf16 words; W0/W1 word i2 = toks {2i2, 2i2+1} of crow order
    float psum = 0.f;
    unsigned W0[8], W1[8];
#pragma unroll
    for (int i2 = 0; i2 < 8; ++i2) {
      const float e0 = __expf(sc0[2 * i2] - m_run);
      const float e1 = __expf(sc0[2 * i2 + 1] - m_run);
      const float f0 = __expf(sc1[2 * i2] - m_run);
      const float f1 = __expf(sc1[2 * i2 + 1] - m_run);
      psum += (e0 + e1) + (f0 + f1);
      W0[i2] = pk2(e0, e1);
      W1[i2] = pk2(f0, f1);
    }
    psum += __shfl_xor(psum, 32);
    l_run += psum;

    // ---- PV: per k-slice s (16 toks), assemble P B-frag via shfl_xor(32) ----
#pragma unroll
    for (int s4 = 0; s4 < 4; ++s4) {
      const int u = s4 & 1;
      const unsigned a0 = (s4 < 2) ? W0[4 * u + 0] : W1[4 * u + 0];
      const unsigned a1 = (s4 < 2) ? W0[4 * u + 1] : W1[4 * u + 1];
      const unsigned a2 = (s4 < 2) ? W0[4 * u + 2] : W1[4 * u + 2];
      const unsigned a3 = (s4 < 2) ? W0[4 * u + 3] : W1[4 * u + 3];
      const unsigned x0 = (unsigned)__shfl_xor((int)a0, 32);
      const unsigned x1 = (unsigned)__shfl_xor((int)a1, 32);
      const unsigned x2 = (unsigned)__shfl_xor((int)a2, 32);
      const unsigned x3 = (unsigned)__shfl_xor((int)a3, 32);
      union { unsigned u4[4]; bf16x8 v; } pa;
      pa.u4[0] = hi ? x2 : a0;
      pa.u4[1] = hi ? x3 : a1;
      pa.u4[2] = hi ? a2 : x0;
      pa.u4[3] = hi ? a3 : x1;
      const int cb = 32 * s4 + 16 * hi;
#pragma unroll
      for (int dh = 0; dh < 2; ++dh) {
        const int vr = 32 * dh + l31;
        const unsigned ov = ((unsigned)((vr << 7) | cb)) ^ ((vr & 7) << 4);
        const bf16x8 va = *(const bf16x8*)(vtb + ov);
        if (dh == 0)
          oacc0 = __builtin_amdgcn_mfma_f32_32x32x16_bf16(va, pa.v, oacc0, 0, 0, 0);
        else
          oacc1 = __builtin_amdgcn_mfma_f32_32x32x16_bf16(va, pa.v, oacc1, 0, 0, 0);
      }
    }
    __syncthreads();
  }

  // ---- write partials: O[q][d], d = 32*dh + 8*g + 4*hi + {0..3} <- regs 4g+j
  if (qrow < NT) {
    float* Op = Opart + (((size_t)strip * NH + h) * NT + qrow) * HD;
#pragma unroll
    for (int g = 0; g < 4; ++g) {
      f32x4 o0 = {oacc0[4 * g], oacc0[4 * g + 1], oacc0[4 * g + 2], oacc0[4 * g + 3]};
      f32x4 o1 = {oacc1[4 * g], oacc1[4 * g + 1], oacc1[4 * g + 2], oacc1[4 * g + 3]};
      *(f32x4*)(Op + 8 * g + 4 * hi) = o0;
      *(f32x4*)(Op + 32 + 8 * g + 4 * hi) = o1;
    }
    if (hi == 0)
      mlpart[((size_t)strip * NH + h) * NT + qrow] = make_float2(m_run, l_run);
  }
}

// ---------------------------------------------------------------------------
// Combine the SSTR stripes.
// ---------------------------------------------------------------------------
__global__ __launch_bounds__(256) void attn_merge(
    const float* __restrict__ Opart, const float2* __restrict__ mlpart,
    float* __restrict__ Ow) {
  const int idx = blockIdx.x * 256 + threadIdx.x;
  if (idx >= NH * NT * HD) return;
  const int d = idx & 63;
  const int hn = idx >> 6;
  const int n = hn % NT;
  const int h = hn / NT;
  float M = -1e30f;
  float m[SSTR], lv[SSTR];
#pragma unroll
  for (int s = 0; s < SSTR; ++s) {
    const float2 ml = mlpart[((size_t)s * NH + h) * NT + n];
    m[s] = ml.x; lv[s] = ml.y;
    M = fmaxf(M, m[s]);
  }
  float L = 0.f, O = 0.f;
#pragma unroll
  for (int s = 0; s < SSTR; ++s) {
    const float e = __expf(m[s] - M);
    L += lv[s] * e;
    O += Opart[(((size_t)s * NH + h) * NT + n) * HD + d] * e;
  }
  Ow[(size_t)n * CC + h * HD + d] = O / L;
}

// ---------------------------------------------------------------------------
// fp32 proj GEMM: out[m][c] = Ow[m,:] . proj_w[c,:] + b
// ---------------------------------------------------------------------------
__global__ __launch_bounds__(256) void gemm_proj(
    const float* __restrict__ A, const float* __restrict__ W,
    const float* __restrict__ bias, float* __restrict__ out_f) {
  __shared__ float xs[32][36];
  __shared__ float wsT[32][68];
  const int tid = threadIdx.x;
  const int tx = tid & 15, ty = tid >> 4;
  const int bm = blockIdx.y * 32, bn = blockIdx.x * 64;
  float acc[2][4] = {{0.f, 0.f, 0.f, 0.f}, {0.f, 0.f, 0.f, 0.f}};
  for (int k0 = 0; k0 < CC; k0 += 32) {
    {
      const int r = tid >> 3, kq = (tid & 7) << 2;
      *(float4*)&xs[r][kq] = *(const float4*)(A + (size_t)(bm + r) * CC + k0 + kq);
    }
#pragma unroll
    for (int e0 = 0; e0 < 2; ++e0) {
      const int e = tid + e0 * 256;
      const int r = e >> 3, kq = (e & 7) << 2;
      float4 v = *(const float4*)(W + (size_t)(bn + r) * CC + k0 + kq);
      wsT[kq + 0][r] = v.x; wsT[kq + 1][r] = v.y;
      wsT[kq + 2][r] = v.z; wsT[kq + 3][r] = v.w;
    }
    __syncthreads();
#pragma unroll
    for (int kk = 0; kk < 32; ++kk) {
      const float a0 = xs[ty * 2 + 0][kk];
      const float a1 = xs[ty * 2 + 1][kk];
      const float4 b = *(const float4*)&wsT[kk][tx * 4];
      acc[0][0] = fmaf(a0, b.x, acc[0][0]); acc[0][1] = fmaf(a0, b.y, acc[0][1]);
      acc[0][2] = fmaf(a0, b.z, acc[0][2]); acc[0][3] = fmaf(a0, b.w, acc[0][3]);
      acc[1][0] = fmaf(a1, b.x, acc[1][0]); acc[1][1] = fmaf(a1, b.y, acc[1][1]);
      acc[1][2] = fmaf(a1, b.z, acc[1][2]); acc[1][3] = fmaf(a1, b.w, acc[1][3]);
    }
    __syncthreads();
  }
#pragma unroll
  for (int i = 0; i < 2; ++i)
#pragma unroll
    for (int j = 0; j < 4; ++j) {
      const int m = bm + ty * 2 + i, c = bn + tx * 4 + j;
      out_f[(size_t)m * CC + c] = acc[i][j] + bias[c];
    }
}

// ---------------------------------------------------------------------------
extern "C" void kernel_launch(void* const* d_in, const int* in_sizes, int n_in,
                              void* d_out, int out_size, void* d_ws,
                              size_t ws_size, hipStream_t stream) {
  const float* x       = (const float*)d_in[0];
  const float* qkv_w   = (const float*)d_in[1];
  const float* qkv_b   = (const float*)d_in[2];
  const float* proj_w  = (const float*)d_in[3];
  const float* proj_b  = (const float*)d_in[4];
  const float* k_cache = (const float*)d_in[5];
  const float* v_cache = (const float*)d_in[6];
  const float* k_specl = (const float*)d_in[7];
  const float* v_specl = (const float*)d_in[8];
  float* out = (float*)d_out;

  const size_t qb_bytes = (size_t)NH * NT * HD * 2;          //    884,736
  const size_t kv_bytes = (size_t)NH * MP * HD * 2;          // 21,430,272
  const size_t xb_bytes = (size_t)NT * CC * 2;               //    884,736
  const size_t op_bytes = (size_t)SSTR * NH * NT * HD * 4;   // 28,311,552
  const size_t ml_bytes = (size_t)SSTR * NH * NT * 8;        //    884,736

  char* ws = (char*)d_ws;
  __hip_bfloat16* Qb = (__hip_bfloat16*)ws;
  __hip_bfloat16* Kf = (__hip_bfloat16*)(ws + qb_bytes);
  __hip_bfloat16* Vt = (__hip_bfloat16*)(ws + qb_bytes + kv_bytes);
  char* opp = ws + qb_bytes + 2 * kv_bytes;
  float* Opart = (float*)opp;
  __hip_bfloat16* xb = (__hip_bfloat16*)opp;                 // alias under Opart
  __hip_bfloat16* wb = (__hip_bfloat16*)(opp + xb_bytes);    // alias under Opart
  float2* mlpart = (float2*)(opp + op_bytes);
  float* Ow = (float*)(opp + op_bytes + ml_bytes);

  // 1) bf16 copies of x and qkv_w (fused)
  cvt_all<<<dim3(1080), 256, 0, stream>>>(x, qkv_w, xb, wb);
  // 2) fused QKV projection + K/V gathers (disjoint writes, overlapped exec)
  qkv_and_gather<<<dim3(GEMM_BLKS + VT_BLKS + KB_BLKS), 256, 0, stream>>>(
      xb, wb, qkv_b, Qb, Kf, Vt, k_cache, k_specl, v_cache, v_specl);
  // 3) attention partials (5 qtiles x 12 heads x 16 stripes) + merge
  attn_partial<<<dim3(5 * NH * SSTR), 256, 0, stream>>>(Qb, Kf, Vt, Opart, mlpart);
  attn_merge<<<dim3((NH * NT * HD + 255) / 256), 256, 0, stream>>>(Opart, mlpart, Ow);
  // 4) output projection (fp32)
  gemm_proj<<<dim3(12, 18), 256, 0, stream>>>(Ow, proj_w, proj_b, out);
}